// Round 16
// baseline (369.289 us; speedup 1.0000x reference)
//
#include <hip/hip_runtime.h>
#include <hip/hip_bf16.h>
#include <stdint.h>

#define NN 50000
#define EE 800000
#define BB 512
#define HH 96
#define DIN 5
#define DOUT 192
#define EPSV 1e-5f
#define NBANK 32
#define HWS 48                      // bf16 row stride in words (192 B)
#define NSLICE 4
#define SLICEN 12500                // nodes per src-slice (2.4 MB of hwb < 4MB L2)
#define NBUK2 2048                  // NSLICE * 512 (slice,dst-range) buckets
#define BUKN 98
#define FILLB 128
#define FCHUNK (EE / FILLB)         // 6250
#define NNP1 (NN + 1)
#define CHUNK0 25088                // 256 buckets * 98
#define PARTN 25088

__device__ inline float blo(uint32_t w) { return __uint_as_float(w << 16); }
__device__ inline float bhi(uint32_t w) { return __uint_as_float(w & 0xffff0000u); }
__device__ inline uint32_t packbf(float a, float b) {
    uint32_t ua = __float_as_uint(a); ua += 0x7fffu + ((ua >> 16) & 1u);
    uint32_t ub = __float_as_uint(b); ub += 0x7fffu + ((ub >> 16) & 1u);
    return (ua >> 16) | (ub & 0xffff0000u);
}

// ---------------- CSR stage 1: per-block (slice,dst-range) histogram ----------------
__global__ __launch_bounds__(256) void k_bhist(const int* __restrict__ src,
                                               const int* __restrict__ dst,
                                               int* __restrict__ histgb) {
    __shared__ int hist[NBUK2];
    int tid = threadIdx.x;
    for (int j = tid; j < NBUK2; j += 256) hist[j] = 0;
    __syncthreads();
    int e0 = blockIdx.x * FCHUNK;
    for (int e = e0 + tid; e < e0 + FCHUNK; e += 256) {
        int b2 = (src[e] / SLICEN) * 512 + dst[e] / BUKN;
        atomicAdd(&hist[b2], 1);
    }
    __syncthreads();
    for (int j = tid; j < NBUK2; j += 256) histgb[blockIdx.x * NBUK2 + j] = hist[j];
}

// ---------------- CSR stage 2: per-(block,bucket) bases + bucket scan ----------------
__global__ __launch_bounds__(1024) void k_bscan(int* __restrict__ histgb,
                                                int* __restrict__ bkbase,
                                                float* __restrict__ stats,
                                                int* __restrict__ rp2s) {
    __shared__ int sc[NBUK2];
    int t = threadIdx.x;
    for (int i = t; i < 2 * NBANK * 192; i += 1024) stats[i] = 0.0f;
    for (int j = t; j < NBUK2; j += 1024) {
        int c = 0;
        for (int b = 0; b < FILLB; ++b) {
            int idx = b * NBUK2 + j;
            int tmp = histgb[idx];
            histgb[idx] = c;
            c += tmp;
        }
        sc[j] = c;
    }
    __syncthreads();
    if (t == 0) {
        int c = 0;
        for (int j = 0; j < NBUK2; ++j) { int s0 = sc[j]; sc[j] = c; c += s0; }
        bkbase[NBUK2] = c;   // == EE
    }
    __syncthreads();
    for (int j = t; j < NBUK2; j += 1024) bkbase[j] = sc[j];
    if (t < NSLICE) rp2s[(size_t)t * NNP1 + NN] = (t == NSLICE - 1) ? EE : sc[(t + 1) * 512];
}

// ---------------- CSR stage 3: single-pass scatter into (slice,dst) buckets ----------
__global__ __launch_bounds__(256) void k_bscat(const int* __restrict__ src,
                                               const int* __restrict__ dst,
                                               const int* __restrict__ histgb,
                                               const int* __restrict__ bkbase,
                                               uint32_t* __restrict__ ebuf) {
    __shared__ int bbase[NBUK2], cnt[NBUK2];
    int tid = threadIdx.x;
    for (int j = tid; j < NBUK2; j += 256) {
        bbase[j] = bkbase[j] + histgb[blockIdx.x * NBUK2 + j];
        cnt[j] = 0;
    }
    __syncthreads();
    int e0 = blockIdx.x * FCHUNK, e1 = e0 + FCHUNK;
    for (int e = e0 + tid; e < e1; e += 256) {
        int sv = src[e], d = dst[e];
        int db = d / BUKN;
        int b2 = (sv / SLICEN) * 512 + db;
        int off = atomicAdd(&cnt[b2], 1);
        ebuf[bbase[b2] + off] = (uint32_t)sv | ((uint32_t)(d - db * BUKN) << 16);
    }
}

// ---------------- CSR stage 4: per-bucket count/scan -> rp2s, colp ----------------
__global__ __launch_bounds__(256) void k_csr(const uint32_t* __restrict__ ebuf,
                                             const int* __restrict__ bkbase,
                                             int* __restrict__ rp2s,
                                             int* __restrict__ colp) {
    __shared__ int cnt[BUKN], base[BUKN], lcur[BUKN];
    int bk = blockIdx.x, tid = threadIdx.x;
    int s = bk >> 9;          // bucket slice
    int b = bk & 511;
    int node0 = b * BUKN;
    if (node0 >= NN) return;
    int nn = min(BUKN, NN - node0);
    int ebase = bkbase[bk], eend = bkbase[bk + 1];
    for (int j = tid; j < nn; j += 256) { cnt[j] = 0; lcur[j] = 0; }
    __syncthreads();
    for (int i = ebase + tid; i < eend; i += 256) atomicAdd(&cnt[ebuf[i] >> 16], 1);
    __syncthreads();
    if (tid == 0) {
        int c = 0;
        for (int j = 0; j < nn; ++j) { base[j] = c; c += cnt[j]; }
    }
    __syncthreads();
    for (int j = tid; j < nn; j += 256)
        rp2s[(size_t)s * NNP1 + node0 + j] = ebase + base[j];
    for (int i = ebase + tid; i < eend; i += 256) {
        uint32_t w = ebuf[i];
        int dr = (int)(w >> 16);
        int off = atomicAdd(&lcur[dr], 1);
        colp[ebase + base[dr] + off] = (int)(w & 0xffffu);
    }
}

// ---------------- degrees + dinv + per-bucket degree hist from rp2s ----------------
__global__ __launch_bounds__(128) void k_deg(const int* __restrict__ rp2s,
                                             int* __restrict__ degi,
                                             float* __restrict__ dinv,
                                             int* __restrict__ dhistb) {
    __shared__ int dh[64];
    int b = blockIdx.x, t = threadIdx.x;
    if (t < 64) dh[t] = 0;
    __syncthreads();
    int node0 = b * BUKN;
    if (node0 < NN) {
        int nn = min(BUKN, NN - node0);
        if (t < nn) {
            int n = node0 + t;
            int deg = 0;
#pragma unroll
            for (int s = 0; s < NSLICE; ++s)
                deg += rp2s[(size_t)s * NNP1 + n + 1] - rp2s[(size_t)s * NNP1 + n];
            degi[n] = deg;
            dinv[n] = rsqrtf((float)deg + 1.0f);
            atomicAdd(&dh[min(deg, 63)], 1);
        }
    }
    __syncthreads();
    if (t < 64) dhistb[b * 64 + t] = dh[t];
}

// ---------------- per-half scan of degree hists -> per-(bucket,bin) bases ------------
__global__ __launch_bounds__(64) void k_dscan(int* __restrict__ dhistb) {
    __shared__ int tot[64], binbase[64];
    int t = threadIdx.x;
    for (int h = 0; h < 2; ++h) {
        int b0 = h * 256, b1 = b0 + 256;
        int s = 0;
        for (int b = b0; b < b1; ++b) s += dhistb[b * 64 + t];
        tot[t] = s;
        __syncthreads();
        if (t == 0) {
            int c = h * CHUNK0;
            for (int k = 0; k < 64; ++k) { binbase[k] = c; c += tot[k]; }
        }
        __syncthreads();
        int c = binbase[t];
        for (int b = b0; b < b1; ++b) {
            int tmp = dhistb[b * 64 + t];
            dhistb[b * 64 + t] = c;
            c += tmp;
        }
        __syncthreads();
    }
}

// ---------------- degree-sorted permutation: per-bucket LDS cursors ------------------
__global__ __launch_bounds__(128) void k_dperm(const int* __restrict__ degi,
                                               const int* __restrict__ dhistb,
                                               int* __restrict__ perm) {
    __shared__ int lcur[64];
    int b = blockIdx.x, t = threadIdx.x;
    int node0 = b * BUKN;
    if (node0 >= NN) return;
    int nn = min(BUKN, NN - node0);
    if (t < 64) lcur[t] = dhistb[b * 64 + t];
    __syncthreads();
    if (t < nn) {
        int i = node0 + t;
        int pos = atomicAdd(&lcur[min(degi[i], 63)], 1);
        perm[pos] = i;
    }
}

// ---- helper: pack 24 f32 -> 12 words at row offset q*12 ----
__device__ inline void pack24(uint32_t* __restrict__ dstrow, int q, const float* v) {
    uint32_t wv[12];
#pragma unroll
    for (int p = 0; p < 12; ++p) wv[p] = packbf(v[2 * p], v[2 * p + 1]);
    uint4* dstp = reinterpret_cast<uint4*>(dstrow + q * 12);
    dstp[0] = make_uint4(wv[0], wv[1], wv[2], wv[3]);
    dstp[1] = make_uint4(wv[4], wv[5], wv[6], wv[7]);
    dstp[2] = make_uint4(wv[8], wv[9], wv[10], wv[11]);
}

// ---------------- fused input layer + GEMM1 -> h0b (bf16), hwb (prescaled bf16) ------
__global__ __launch_bounds__(256) void k_gemm_in(const float* __restrict__ x,
                                                 const float* __restrict__ Win,
                                                 const float* __restrict__ bin,
                                                 const float* __restrict__ W1,
                                                 const float* __restrict__ dinv,
                                                 uint32_t* __restrict__ h0b,
                                                 uint32_t* __restrict__ hwb) {
    __shared__ float sAT[96][68];
    __shared__ float sW[96 * 96];
    int tid = threadIdx.x;
    int row0 = blockIdx.x * 64;

    for (int i = tid; i < 96 * 96; i += 256) sW[i] = W1[i];

    {
        int r = tid >> 2, q = tid & 3;
        int j0q = q * 24;
        int gr = row0 + r;
        float xv[5];
#pragma unroll
        for (int k = 0; k < DIN; ++k) xv[k] = (gr < NN) ? x[gr * DIN + k] : 0.0f;
        float hv[24];
#pragma unroll
        for (int jj = 0; jj < 24; ++jj) {
            float acc = bin[j0q + jj];
#pragma unroll
            for (int k = 0; k < DIN; ++k) acc += xv[k] * Win[k * 96 + j0q + jj];
            hv[jj] = fmaxf(acc, 0.0f);
            sAT[j0q + jj][r] = hv[jj];
        }
        if (gr < NN) pack24(&h0b[(size_t)gr * HWS], q, hv);
    }
    __syncthreads();

    int tc = tid & 15, tr = tid >> 4;
    int r0 = tr * 4, j0 = tc * 6;
    float acc[4][6];
#pragma unroll
    for (int i = 0; i < 4; ++i)
#pragma unroll
        for (int j = 0; j < 6; ++j) acc[i][j] = 0.0f;

    for (int k = 0; k < 96; ++k) {
        float4 a = *reinterpret_cast<const float4*>(&sAT[k][r0]);
        const float* wr = &sW[k * 96 + j0];
        float b0 = wr[0], b1 = wr[1], b2 = wr[2], b3 = wr[3], b4 = wr[4], b5 = wr[5];
        float av[4] = {a.x, a.y, a.z, a.w};
#pragma unroll
        for (int i = 0; i < 4; ++i) {
            acc[i][0] += av[i] * b0; acc[i][1] += av[i] * b1; acc[i][2] += av[i] * b2;
            acc[i][3] += av[i] * b3; acc[i][4] += av[i] * b4; acc[i][5] += av[i] * b5;
        }
    }
#pragma unroll
    for (int i = 0; i < 4; ++i) {
        int gr = row0 + r0 + i;
        if (gr < NN) {
            float dv = dinv[gr];
            uint32_t* wp = &hwb[(size_t)gr * HWS + tc * 3];
            wp[0] = packbf(acc[i][0] * dv, acc[i][1] * dv);
            wp[1] = packbf(acc[i][2] * dv, acc[i][3] * dv);
            wp[2] = packbf(acc[i][4] * dv, acc[i][5] * dv);
        }
    }
}

// ---------------- gather pass A: per-slice partial sums (slice L2-resident) ----------
__global__ __launch_bounds__(256) void k_gatherA(const uint32_t* __restrict__ hwb,
                                                 const int* __restrict__ rp2s,
                                                 const int* __restrict__ colp,
                                                 const int* __restrict__ perm,
                                                 int chunkbase,
                                                 uint32_t* __restrict__ partial) {
    int tid = threadIdx.x;
    int t = tid & 15, slot = tid >> 4;
    int s = blockIdx.x & 3, g = blockIdx.x >> 2;   // slice -> XCD {s, s+4}
    int pos = chunkbase + g * 16 + slot;
    int n = perm[pos];
    const int* rp = rp2s + (size_t)s * NNP1 + n;
    int p = rp[0], end = rp[1];
    float a0 = 0.f, a1 = 0.f, a2 = 0.f, a3 = 0.f, a4 = 0.f, a5 = 0.f;
    for (; p + 1 < end; p += 2) {
        int s0 = colp[p], s1 = colp[p + 1];
        const uint32_t* r0 = hwb + (size_t)s0 * HWS;
        const uint32_t* r1 = hwb + (size_t)s1 * HWS;
        uint2 u0 = *reinterpret_cast<const uint2*>(r0 + 2 * t); uint32_t v0 = r0[32 + t];
        uint2 u1 = *reinterpret_cast<const uint2*>(r1 + 2 * t); uint32_t v1 = r1[32 + t];
        a0 += blo(u0.x); a1 += bhi(u0.x); a2 += blo(u0.y); a3 += bhi(u0.y);
        a4 += blo(v0);   a5 += bhi(v0);
        a0 += blo(u1.x); a1 += bhi(u1.x); a2 += blo(u1.y); a3 += bhi(u1.y);
        a4 += blo(v1);   a5 += bhi(v1);
    }
    if (p < end) {
        const uint32_t* rs = hwb + (size_t)colp[p] * HWS;
        uint2 u = *reinterpret_cast<const uint2*>(rs + 2 * t);
        uint32_t v = rs[32 + t];
        a0 += blo(u.x); a1 += bhi(u.x); a2 += blo(u.y); a3 += bhi(u.y);
        a4 += blo(v);   a5 += bhi(v);
    }
    uint32_t* pp = partial + ((size_t)s * PARTN + (pos - chunkbase)) * HWS;
    *reinterpret_cast<uint2*>(pp + 2 * t) = make_uint2(packbf(a0, a1), packbf(a2, a3));
    pp[32 + t] = packbf(a4, a5);
}

// ---------------- gather pass B: combine self + 4 partials, scale, stats -------------
__global__ __launch_bounds__(256) void k_gatherB(const uint32_t* __restrict__ hwb,
                                                 const uint32_t* __restrict__ partial,
                                                 const float* __restrict__ dinv,
                                                 const int* __restrict__ perm,
                                                 int chunkbase,
                                                 uint32_t* __restrict__ aggb,
                                                 float* __restrict__ stats) {
    int tid = threadIdx.x;
    int t = tid & 15, slot = tid >> 4;
    int pos = chunkbase + blockIdx.x * 16 + slot;
    int n = perm[pos];
    const uint32_t* rn = hwb + (size_t)n * HWS;
    uint2 w01 = *reinterpret_cast<const uint2*>(rn + 2 * t);
    uint32_t w2 = rn[32 + t];
    float a0 = blo(w01.x), a1 = bhi(w01.x);
    float a2 = blo(w01.y), a3 = bhi(w01.y);
    float a4 = blo(w2),    a5 = bhi(w2);
#pragma unroll
    for (int s = 0; s < NSLICE; ++s) {
        const uint32_t* pr = partial + ((size_t)s * PARTN + (pos - chunkbase)) * HWS;
        uint2 u = *reinterpret_cast<const uint2*>(pr + 2 * t);
        uint32_t v = pr[32 + t];
        a0 += blo(u.x); a1 += bhi(u.x); a2 += blo(u.y); a3 += bhi(u.y);
        a4 += blo(v);   a5 += bhi(v);
    }
    float dn = dinv[n];
    a0 *= dn; a1 *= dn; a2 *= dn; a3 *= dn; a4 *= dn; a5 *= dn;

    uint32_t* an = aggb + (size_t)n * HWS;
    *reinterpret_cast<uint2*>(an + 2 * t) = make_uint2(packbf(a0, a1), packbf(a2, a3));
    an[32 + t] = packbf(a4, a5);

    __shared__ float red[2][96];
    if (tid < 96) { red[0][tid] = 0.0f; red[1][tid] = 0.0f; }
    __syncthreads();
    int colsv[6] = {4 * t, 4 * t + 1, 4 * t + 2, 4 * t + 3, 64 + 2 * t, 64 + 2 * t + 1};
    float cs[6] = {a0, a1, a2, a3, a4, a5};
#pragma unroll
    for (int k = 0; k < 6; ++k) {
        atomicAdd(&red[0][colsv[k]], cs[k]);
        atomicAdd(&red[1][colsv[k]], cs[k] * cs[k]);
    }
    __syncthreads();
    float* bank = stats + (blockIdx.x & (NBANK - 1)) * 192;
    if (tid < 96) {
        atomicAdd(&bank[tid], red[0][tid]);
        atomicAdd(&bank[96 + tid], red[1][tid]);
    }
}

// ---------------- fused BN+ReLU+residual + GEMM -> h1b (bf16), hwb (prescaled) -------
__global__ __launch_bounds__(256) void k_gemm_bn(const uint32_t* __restrict__ aggb,
                                                 const uint32_t* __restrict__ hprevb,
                                                 const float* __restrict__ stats,
                                                 const float* __restrict__ g,
                                                 const float* __restrict__ be,
                                                 const float* __restrict__ W,
                                                 const float* __restrict__ dinv,
                                                 uint32_t* __restrict__ hnewb,
                                                 uint32_t* __restrict__ hwb) {
    __shared__ float sAT[96][68];
    __shared__ float sW[96 * 96];
    __shared__ float ssc[96], ssh[96];
    int tid = threadIdx.x;
    int row0 = blockIdx.x * 64;

    for (int i = tid; i < 96 * 96; i += 256) sW[i] = W[i];
    if (tid < 96) {
        float s = 0.0f, s2 = 0.0f;
#pragma unroll
        for (int k = 0; k < NBANK; ++k) { s += stats[k * 192 + tid]; s2 += stats[k * 192 + 96 + tid]; }
        float m = s * (1.0f / NN);
        float var = s2 * (1.0f / NN) - m * m;
        float sc = g[tid] * rsqrtf(var + EPSV);
        ssc[tid] = sc;
        ssh[tid] = be[tid] - m * sc;
    }
    __syncthreads();

    for (int i = tid; i < 64 * 24; i += 256) {
        int r = i / 24, qq = i % 24;
        int gr = row0 + r, c = qq * 4, w0 = qq * 2;
        float v0 = 0.0f, v1 = 0.0f, v2 = 0.0f, v3 = 0.0f;
        if (gr < NN) {
            uint2 aw = *reinterpret_cast<const uint2*>(&aggb[(size_t)gr * HWS + w0]);
            uint2 pw = *reinterpret_cast<const uint2*>(&hprevb[(size_t)gr * HWS + w0]);
            v0 = fmaxf(blo(aw.x) * ssc[c]     + ssh[c],     0.0f) + blo(pw.x);
            v1 = fmaxf(bhi(aw.x) * ssc[c + 1] + ssh[c + 1], 0.0f) + bhi(pw.x);
            v2 = fmaxf(blo(aw.y) * ssc[c + 2] + ssh[c + 2], 0.0f) + blo(pw.y);
            v3 = fmaxf(bhi(aw.y) * ssc[c + 3] + ssh[c + 3], 0.0f) + bhi(pw.y);
            *reinterpret_cast<uint2*>(&hnewb[(size_t)gr * HWS + w0]) =
                make_uint2(packbf(v0, v1), packbf(v2, v3));
        }
        sAT[c][r] = v0; sAT[c + 1][r] = v1; sAT[c + 2][r] = v2; sAT[c + 3][r] = v3;
    }
    __syncthreads();

    int tc = tid & 15, tr = tid >> 4;
    int r0 = tr * 4, j0 = tc * 6;
    float acc[4][6];
#pragma unroll
    for (int i = 0; i < 4; ++i)
#pragma unroll
        for (int j = 0; j < 6; ++j) acc[i][j] = 0.0f;

    for (int k = 0; k < 96; ++k) {
        float4 a = *reinterpret_cast<const float4*>(&sAT[k][r0]);
        const float* wr = &sW[k * 96 + j0];
        float b0 = wr[0], b1 = wr[1], b2 = wr[2], b3 = wr[3], b4 = wr[4], b5 = wr[5];
        float av[4] = {a.x, a.y, a.z, a.w};
#pragma unroll
        for (int i = 0; i < 4; ++i) {
            acc[i][0] += av[i] * b0; acc[i][1] += av[i] * b1; acc[i][2] += av[i] * b2;
            acc[i][3] += av[i] * b3; acc[i][4] += av[i] * b4; acc[i][5] += av[i] * b5;
        }
    }
#pragma unroll
    for (int i = 0; i < 4; ++i) {
        int gr = row0 + r0 + i;
        if (gr < NN) {
            float dv = dinv[gr];
            uint32_t* wp = &hwb[(size_t)gr * HWS + tc * 3];
            wp[0] = packbf(acc[i][0] * dv, acc[i][1] * dv);
            wp[1] = packbf(acc[i][2] * dv, acc[i][3] * dv);
            wp[2] = packbf(acc[i][4] * dv, acc[i][5] * dv);
        }
    }
}

// ---------------- fused BN2 + pool + GEMM(96x192) + LayerNorm ----------------
__device__ inline int lower_bound_i(const int* __restrict__ a, int n, int v) {
    int lo = 0, hi = n;
    while (lo < hi) { int mid = (lo + hi) >> 1; if (a[mid] < v) lo = mid + 1; else hi = mid; }
    return lo;
}

__global__ __launch_bounds__(384) void k_out(const uint32_t* __restrict__ aggb,
                                             const uint32_t* __restrict__ hprevb,
                                             const float* __restrict__ stats,
                                             const float* __restrict__ g,
                                             const float* __restrict__ be,
                                             const int* __restrict__ batch,
                                             const float* __restrict__ Wout,
                                             const float* __restrict__ bout,
                                             const float* __restrict__ lg,
                                             const float* __restrict__ lb,
                                             float* __restrict__ out) {
    __shared__ float ssc[96], ssh[96];
    __shared__ float sp8[8][96];
    __shared__ float sp[96];
    __shared__ float svals[192];
    __shared__ float smv[2];
    int b = blockIdx.x, t = threadIdx.x;
    if (t < 96) {
        float s = 0.0f, s2 = 0.0f;
#pragma unroll
        for (int k = 0; k < NBANK; ++k) { s += stats[k * 192 + t]; s2 += stats[k * 192 + 96 + t]; }
        float m = s * (1.0f / NN);
        float var = s2 * (1.0f / NN) - m * m;
        float sc = g[t] * rsqrtf(var + EPSV);
        ssc[t] = sc;
        ssh[t] = be[t] - m * sc;
    }
    int lo = lower_bound_i(batch, NN, b);
    int hi = lower_bound_i(batch, NN, b + 1);
    __syncthreads();

    int w = t % 48, qr = t / 48;
    int c0 = 2 * w, c1 = 2 * w + 1;
    float sc0 = ssc[c0], sh0 = ssh[c0], sc1 = ssc[c1], sh1 = ssh[c1];
    float accp0 = 0.0f, accp1 = 0.0f;
    for (int r = lo + qr; r < hi; r += 8) {
        uint32_t a = aggb[(size_t)r * HWS + w];
        uint32_t h = hprevb[(size_t)r * HWS + w];
        accp0 += fmaxf(blo(a) * sc0 + sh0, 0.0f) + blo(h);
        accp1 += fmaxf(bhi(a) * sc1 + sh1, 0.0f) + bhi(h);
    }
    sp8[qr][c0] = accp0;
    sp8[qr][c1] = accp1;
    __syncthreads();
    if (t < 96) {
        float inv = (hi > lo) ? 1.0f / (float)(hi - lo) : 0.0f;
        float s = 0.0f;
#pragma unroll
        for (int k = 0; k < 8; ++k) s += sp8[k][t];
        sp[t] = s * inv;
    }
    __syncthreads();

    float acc = 0.0f;
    if (t < 192) {
        acc = bout[t];
        for (int k = 0; k < 96; ++k) acc += sp[k] * Wout[k * 192 + t];
        svals[t] = acc;
    }
    __syncthreads();
    if (t < 64) {
        float a0 = svals[t], a1 = svals[t + 64], a2 = svals[t + 128];
        float s = a0 + a1 + a2;
        float s2 = a0 * a0 + a1 * a1 + a2 * a2;
        for (int o = 32; o > 0; o >>= 1) {
            s += __shfl_down(s, o, 64);
            s2 += __shfl_down(s2, o, 64);
        }
        if (t == 0) { smv[0] = s * (1.0f / 192.0f); smv[1] = s2 * (1.0f / 192.0f); }
    }
    __syncthreads();
    if (t < 192) {
        float m = smv[0];
        float var = smv[1] - m * m;
        float rr = rsqrtf(var + EPSV);
        out[b * 192 + t] = lg[t] * (acc - m) * rr + lb[t];
    }
}

extern "C" void kernel_launch(void* const* d_in, const int* in_sizes, int n_in,
                              void* d_out, int out_size, void* d_ws, size_t ws_size,
                              hipStream_t stream) {
    const float* x    = (const float*)d_in[0];
    const int*   ei   = (const int*)  d_in[1];
    const int*   batch= (const int*)  d_in[2];
    const float* Win  = (const float*)d_in[3];
    const float* bin  = (const float*)d_in[4];
    const float* W1   = (const float*)d_in[5];
    const float* g1   = (const float*)d_in[7];
    const float* be1  = (const float*)d_in[8];
    const float* W2   = (const float*)d_in[9];
    const float* g2   = (const float*)d_in[11];
    const float* be2  = (const float*)d_in[12];
    const float* Wout = (const float*)d_in[13];
    const float* bout = (const float*)d_in[14];
    const float* lg   = (const float*)d_in[15];
    const float* lb   = (const float*)d_in[16];
    const int* src = ei;
    const int* dst = ei + EE;

    uint32_t* wsp    = (uint32_t*)d_ws;
    uint32_t* h0b    = wsp;                           // [N][48] bf16x2
    uint32_t* h1b    = h0b + (size_t)NN * HWS;        // [N][48]
    uint32_t* aggb   = h1b + (size_t)NN * HWS;        // [N][48]
    uint32_t* hwb    = aggb + (size_t)NN * HWS;       // [N][48] prescaled
    uint32_t* partial= hwb + (size_t)NN * HWS;        // [NSLICE][PARTN][48]
    float*    dinv   = (float*)(partial + (size_t)NSLICE * PARTN * HWS);  // [N]
    float*    stats  = dinv + NN;                     // [2][NBANK][192]
    int*      degi   = (int*)(stats + 2 * NBANK * 192);   // [N]
    int*      dhistb = degi + NN;                     // [512][64]
    int*      rp2s   = dhistb + 512 * 64;             // [NSLICE][NN+1]
    int*      perm   = rp2s + NSLICE * NNP1;          // [N]
    int*      bkbase = perm + NN;                     // [NBUK2+1]
    int*      histgb = bkbase + NBUK2 + 1;            // [FILLB][NBUK2]
    int*      colp   = histgb + FILLB * NBUK2;        // [E]
    uint32_t* ebuf   = aggb;                          // [E] aliases aggb

    const int TB = 256;
    float* stats1 = stats;
    float* stats2 = stats + NBANK * 192;
    const int chunkbase[2] = {0, CHUNK0};
    const int chunkN[2] = {CHUNK0, NN - CHUNK0};      // 25088, 24912

    // ---- CSR build (slice,dst-major) + degree sort ----
    k_bhist<<<FILLB, TB, 0, stream>>>(src, dst, histgb);
    k_bscan<<<1, 1024, 0, stream>>>(histgb, bkbase, stats, rp2s);
    k_bscat<<<FILLB, TB, 0, stream>>>(src, dst, histgb, bkbase, ebuf);
    k_csr<<<NBUK2, TB, 0, stream>>>(ebuf, bkbase, rp2s, colp);
    k_deg<<<512, 128, 0, stream>>>(rp2s, degi, dinv, dhistb);
    k_dscan<<<1, 64, 0, stream>>>(dhistb);
    k_dperm<<<512, 128, 0, stream>>>(degi, dhistb, perm);

    // ---- layer 0 ----
    k_gemm_in<<<(NN + 63) / 64, TB, 0, stream>>>(x, Win, bin, W1, dinv, h0b, hwb);
    for (int c = 0; c < 2; ++c) {
        k_gatherA<<<(chunkN[c] / 16) * NSLICE, TB, 0, stream>>>(hwb, rp2s, colp, perm,
                                                                chunkbase[c], partial);
        k_gatherB<<<chunkN[c] / 16, TB, 0, stream>>>(hwb, partial, dinv, perm,
                                                     chunkbase[c], aggb, stats1);
    }

    // ---- layer 1 ----
    k_gemm_bn<<<(NN + 63) / 64, TB, 0, stream>>>(aggb, h0b, stats1, g1, be1, W2, dinv,
                                                 h1b, hwb);
    for (int c = 0; c < 2; ++c) {
        k_gatherA<<<(chunkN[c] / 16) * NSLICE, TB, 0, stream>>>(hwb, rp2s, colp, perm,
                                                                chunkbase[c], partial);
        k_gatherB<<<chunkN[c] / 16, TB, 0, stream>>>(hwb, partial, dinv, perm,
                                                     chunkbase[c], aggb, stats2);
    }

    // ---- pool + readout + layernorm ----
    k_out<<<BB, 384, 0, stream>>>(aggb, h1b, stats2, g2, be2, batch, Wout, bout, lg, lb,
                                  (float*)d_out);
}

// Round 17
// 257.725 us; speedup vs baseline: 1.4329x; 1.4329x over previous
//
#include <hip/hip_runtime.h>
#include <hip/hip_bf16.h>
#include <stdint.h>

#define NN 50000
#define EE 800000
#define BB 512
#define HH 96
#define DIN 5
#define DOUT 192
#define EPSV 1e-5f
#define NBANK 32
#define HWS 48                      // bf16 row stride in words (192 B)
#define NB_GATHER 3125              // 3125 * 16 slots = 50000 nodes
#define NBLK_SCAN ((NN + 1023) / 1024)
#define NBUK 512
#define BUKN 98
#define FILLB 128
#define FCHUNK (EE / FILLB)         // 6250

__device__ inline float blo(uint32_t w) { return __uint_as_float(w << 16); }
__device__ inline float bhi(uint32_t w) { return __uint_as_float(w & 0xffff0000u); }
__device__ inline uint32_t packbf(float a, float b) {
    uint32_t ua = __float_as_uint(a); ua += 0x7fffu + ((ua >> 16) & 1u);
    uint32_t ub = __float_as_uint(b); ub += 0x7fffu + ((ub >> 16) & 1u);
    return (ua >> 16) | (ub & 0xffff0000u);
}

// ---------------- CSR stage 1: bucket histogram ----------------
__global__ __launch_bounds__(256) void k_bhist(const int* __restrict__ dst,
                                               int* __restrict__ bkcnt) {
    __shared__ int hist[NBUK];
    int tid = threadIdx.x;
    for (int j = tid; j < NBUK; j += 256) hist[j] = 0;
    __syncthreads();
    int e0 = blockIdx.x * FCHUNK;
    for (int e = e0 + tid; e < e0 + FCHUNK; e += 256) atomicAdd(&hist[dst[e] / BUKN], 1);
    __syncthreads();
    for (int j = tid; j < NBUK; j += 256) if (hist[j]) atomicAdd(&bkcnt[j], hist[j]);
}

// ---------------- CSR stage 2: scan bucket counts; zero stats ----------------
__global__ __launch_bounds__(256) void k_bscan(const int* __restrict__ bkcnt,
                                               int* __restrict__ bkbase,
                                               int* __restrict__ bkcur,
                                               float* __restrict__ stats,
                                               int* __restrict__ row_ptr) {
    __shared__ int sc[NBUK + 1];
    int t = threadIdx.x;
    for (int i = t; i < 2 * NBANK * 192; i += 256) stats[i] = 0.0f;
    for (int j = t; j < NBUK; j += 256) sc[j] = bkcnt[j];
    __syncthreads();
    if (t == 0) {
        int c = 0;
        for (int j = 0; j < NBUK; ++j) { int s = sc[j]; sc[j] = c; c += s; }
        sc[NBUK] = c;
        row_ptr[NN] = c;   // == EE
    }
    __syncthreads();
    for (int j = t; j <= NBUK; j += 256) bkbase[j] = sc[j];
    for (int j = t; j < NBUK; j += 256) bkcur[j] = sc[j];
}

// ---------------- CSR stage 3: scatter edges into bucket regions ----------------
__global__ __launch_bounds__(256) void k_bscat(const int* __restrict__ src,
                                               const int* __restrict__ dst,
                                               int* __restrict__ bkcur,
                                               uint32_t* __restrict__ ebuf) {
    __shared__ int hist[NBUK], bbase[NBUK], cnt[NBUK];
    int tid = threadIdx.x;
    int e0 = blockIdx.x * FCHUNK, e1 = e0 + FCHUNK;
    for (int j = tid; j < NBUK; j += 256) { hist[j] = 0; cnt[j] = 0; }
    __syncthreads();
    for (int e = e0 + tid; e < e1; e += 256) atomicAdd(&hist[dst[e] / BUKN], 1);
    __syncthreads();
    for (int j = tid; j < NBUK; j += 256) bbase[j] = hist[j] ? atomicAdd(&bkcur[j], hist[j]) : 0;
    __syncthreads();
    for (int e = e0 + tid; e < e1; e += 256) {
        int d = dst[e];
        int b = d / BUKN;
        int off = atomicAdd(&cnt[b], 1);
        ebuf[bbase[b] + off] = (uint32_t)src[e] | ((uint32_t)(d - b * BUKN) << 16);
    }
}

// ------- CSR stage 4: per-bucket count/scan -> row_ptr, degi, dinv, col ----------
__global__ __launch_bounds__(256) void k_csr(const uint32_t* __restrict__ ebuf,
                                             const int* __restrict__ bkbase,
                                             int* __restrict__ row_ptr,
                                             int* __restrict__ col,
                                             int* __restrict__ degi,
                                             float* __restrict__ dinv) {
    __shared__ int cnt[BUKN], base[BUKN], lcur[BUKN];
    int b = blockIdx.x, tid = threadIdx.x;
    int node0 = b * BUKN;
    if (node0 >= NN) return;
    int nn = min(BUKN, NN - node0);
    int ebase = bkbase[b], eend = bkbase[b + 1];
    for (int j = tid; j < nn; j += 256) { cnt[j] = 0; lcur[j] = 0; }
    __syncthreads();
    for (int i = ebase + tid; i < eend; i += 256) atomicAdd(&cnt[ebuf[i] >> 16], 1);
    __syncthreads();
    if (tid == 0) {
        int c = 0;
        for (int j = 0; j < nn; ++j) { base[j] = c; c += cnt[j]; }
    }
    __syncthreads();
    for (int j = tid; j < nn; j += 256) {
        row_ptr[node0 + j] = ebase + base[j];
        degi[node0 + j] = cnt[j];
        dinv[node0 + j] = rsqrtf((float)cnt[j] + 1.0f);
    }
    for (int i = ebase + tid; i < eend; i += 256) {
        uint32_t w = ebuf[i];
        int dr = (int)(w >> 16);
        int off = atomicAdd(&lcur[dr], 1);
        col[ebase + base[dr] + off] = (int)(w & 0xffffu);
    }
}

// ---------------- degree histogram per block (counting sort) ----------------
__global__ __launch_bounds__(1024) void k_dhist(const int* __restrict__ degi,
                                                int* __restrict__ histg) {
    __shared__ int dh[64];
    int tid = threadIdx.x;
    if (tid < 64) dh[tid] = 0;
    __syncthreads();
    int i = blockIdx.x * 1024 + tid;
    if (i < NN) atomicAdd(&dh[min(degi[i], 63)], 1);
    __syncthreads();
    if (tid < 64) histg[blockIdx.x * 64 + tid] = dh[tid];
}

__global__ __launch_bounds__(64) void k_dscan(int* __restrict__ histg) {
    __shared__ int tot[64], binbase[64];
    int t = threadIdx.x;
    int s = 0;
    for (int k = 0; k < NBLK_SCAN; ++k) s += histg[k * 64 + t];
    tot[t] = s;
    __syncthreads();
    if (t == 0) {
        int c = 0;
        for (int b2 = 0; b2 < 64; ++b2) { binbase[b2] = c; c += tot[b2]; }
    }
    __syncthreads();
    int c = binbase[t];
    for (int k = 0; k < NBLK_SCAN; ++k) {
        int tmp = histg[k * 64 + t];
        histg[k * 64 + t] = c;
        c += tmp;
    }
}

__global__ __launch_bounds__(1024) void k_dperm(const int* __restrict__ degi,
                                                const int* __restrict__ histg,
                                                int* __restrict__ perm) {
    __shared__ int lcur[64];
    int tid = threadIdx.x;
    if (tid < 64) lcur[tid] = histg[blockIdx.x * 64 + tid];
    __syncthreads();
    int i = blockIdx.x * 1024 + tid;
    if (i < NN) {
        int pos = atomicAdd(&lcur[min(degi[i], 63)], 1);
        perm[pos] = i;
    }
}

// ---- helper: pack 24 f32 -> 12 words at row offset q*12 ----
__device__ inline void pack24(uint32_t* __restrict__ dstrow, int q, const float* v) {
    uint32_t wv[12];
#pragma unroll
    for (int p = 0; p < 12; ++p) wv[p] = packbf(v[2 * p], v[2 * p + 1]);
    uint4* dstp = reinterpret_cast<uint4*>(dstrow + q * 12);
    dstp[0] = make_uint4(wv[0], wv[1], wv[2], wv[3]);
    dstp[1] = make_uint4(wv[4], wv[5], wv[6], wv[7]);
    dstp[2] = make_uint4(wv[8], wv[9], wv[10], wv[11]);
}

// ---------------- fused input layer + GEMM1 -> h0b (bf16), hwb (prescaled bf16) ------
__global__ __launch_bounds__(256) void k_gemm_in(const float* __restrict__ x,
                                                 const float* __restrict__ Win,
                                                 const float* __restrict__ bin,
                                                 const float* __restrict__ W1,
                                                 const float* __restrict__ dinv,
                                                 uint32_t* __restrict__ h0b,
                                                 uint32_t* __restrict__ hwb) {
    __shared__ float sAT[96][68];          // [col][row]
    __shared__ float sW[96 * 96];
    int tid = threadIdx.x;
    int row0 = blockIdx.x * 64;

    for (int i = tid; i < 96 * 96; i += 256) sW[i] = W1[i];

    {   // phase 1: h = relu(x@Win+bin) -> h0b + sAT
        int r = tid >> 2, q = tid & 3;
        int j0q = q * 24;
        int gr = row0 + r;
        float xv[5];
#pragma unroll
        for (int k = 0; k < DIN; ++k) xv[k] = (gr < NN) ? x[gr * DIN + k] : 0.0f;
        float hv[24];
#pragma unroll
        for (int jj = 0; jj < 24; ++jj) {
            float acc = bin[j0q + jj];
#pragma unroll
            for (int k = 0; k < DIN; ++k) acc += xv[k] * Win[k * 96 + j0q + jj];
            hv[jj] = fmaxf(acc, 0.0f);
            sAT[j0q + jj][r] = hv[jj];
        }
        if (gr < NN) pack24(&h0b[(size_t)gr * HWS], q, hv);
    }
    __syncthreads();

    // phase 2: 4x6 register tile
    int tc = tid & 15, tr = tid >> 4;
    int r0 = tr * 4, j0 = tc * 6;
    float acc[4][6];
#pragma unroll
    for (int i = 0; i < 4; ++i)
#pragma unroll
        for (int j = 0; j < 6; ++j) acc[i][j] = 0.0f;

    for (int k = 0; k < 96; ++k) {
        float4 a = *reinterpret_cast<const float4*>(&sAT[k][r0]);
        const float* wr = &sW[k * 96 + j0];
        float b0 = wr[0], b1 = wr[1], b2 = wr[2], b3 = wr[3], b4 = wr[4], b5 = wr[5];
        float av[4] = {a.x, a.y, a.z, a.w};
#pragma unroll
        for (int i = 0; i < 4; ++i) {
            acc[i][0] += av[i] * b0; acc[i][1] += av[i] * b1; acc[i][2] += av[i] * b2;
            acc[i][3] += av[i] * b3; acc[i][4] += av[i] * b4; acc[i][5] += av[i] * b5;
        }
    }
#pragma unroll
    for (int i = 0; i < 4; ++i) {
        int gr = row0 + r0 + i;
        if (gr < NN) {
            float dv = dinv[gr];
            uint32_t* wp = &hwb[(size_t)gr * HWS + tc * 3];
            wp[0] = packbf(acc[i][0] * dv, acc[i][1] * dv);
            wp[1] = packbf(acc[i][2] * dv, acc[i][3] * dv);
            wp[2] = packbf(acc[i][4] * dv, acc[i][5] * dv);
        }
    }
}

// ---------------- gather: prescaled rows, degree-sorted, bf16 agg out ----------------
__global__ __launch_bounds__(256) void k_gather(const uint32_t* __restrict__ hwb,
                                                const float* __restrict__ dinv,
                                                const int* __restrict__ row_ptr,
                                                const int* __restrict__ col,
                                                const int* __restrict__ perm,
                                                uint32_t* __restrict__ aggb,
                                                float* __restrict__ stats) {
    int tid = threadIdx.x;
    int t = tid & 15, slot = tid >> 4;
    int n = perm[blockIdx.x * 16 + slot];

    const uint32_t* rn = hwb + (size_t)n * HWS;
    uint2 w01 = *reinterpret_cast<const uint2*>(rn + 2 * t);
    uint32_t w2 = rn[32 + t];
    float a0 = blo(w01.x), a1 = bhi(w01.x);
    float a2 = blo(w01.y), a3 = bhi(w01.y);
    float a4 = blo(w2),    a5 = bhi(w2);

    int beg = row_ptr[n], end = row_ptr[n + 1];
    int p = beg;
    for (; p + 3 < end; p += 4) {
        int s0 = col[p], s1 = col[p + 1], s2 = col[p + 2], s3 = col[p + 3];
        const uint32_t* r0 = hwb + (size_t)s0 * HWS;
        const uint32_t* r1 = hwb + (size_t)s1 * HWS;
        const uint32_t* r2 = hwb + (size_t)s2 * HWS;
        const uint32_t* r3 = hwb + (size_t)s3 * HWS;
        uint2 u0 = *reinterpret_cast<const uint2*>(r0 + 2 * t); uint32_t v0 = r0[32 + t];
        uint2 u1 = *reinterpret_cast<const uint2*>(r1 + 2 * t); uint32_t v1 = r1[32 + t];
        uint2 u2 = *reinterpret_cast<const uint2*>(r2 + 2 * t); uint32_t v2 = r2[32 + t];
        uint2 u3 = *reinterpret_cast<const uint2*>(r3 + 2 * t); uint32_t v3 = r3[32 + t];
        a0 += blo(u0.x); a1 += bhi(u0.x); a2 += blo(u0.y); a3 += bhi(u0.y);
        a4 += blo(v0);   a5 += bhi(v0);
        a0 += blo(u1.x); a1 += bhi(u1.x); a2 += blo(u1.y); a3 += bhi(u1.y);
        a4 += blo(v1);   a5 += bhi(v1);
        a0 += blo(u2.x); a1 += bhi(u2.x); a2 += blo(u2.y); a3 += bhi(u2.y);
        a4 += blo(v2);   a5 += bhi(v2);
        a0 += blo(u3.x); a1 += bhi(u3.x); a2 += blo(u3.y); a3 += bhi(u3.y);
        a4 += blo(v3);   a5 += bhi(v3);
    }
    for (; p < end; ++p) {
        const uint32_t* rs = hwb + (size_t)col[p] * HWS;
        uint2 u = *reinterpret_cast<const uint2*>(rs + 2 * t);
        uint32_t v = rs[32 + t];
        a0 += blo(u.x); a1 += bhi(u.x);
        a2 += blo(u.y); a3 += bhi(u.y);
        a4 += blo(v);   a5 += bhi(v);
    }
    float dn = dinv[n];
    a0 *= dn; a1 *= dn; a2 *= dn; a3 *= dn; a4 *= dn; a5 *= dn;

    uint32_t* an = aggb + (size_t)n * HWS;
    *reinterpret_cast<uint2*>(an + 2 * t) = make_uint2(packbf(a0, a1), packbf(a2, a3));
    an[32 + t] = packbf(a4, a5);

    __shared__ float red[2][96];
    if (tid < 96) { red[0][tid] = 0.0f; red[1][tid] = 0.0f; }
    __syncthreads();
    int colsv[6] = {4 * t, 4 * t + 1, 4 * t + 2, 4 * t + 3, 64 + 2 * t, 64 + 2 * t + 1};
    float cs[6] = {a0, a1, a2, a3, a4, a5};
#pragma unroll
    for (int k = 0; k < 6; ++k) {
        atomicAdd(&red[0][colsv[k]], cs[k]);
        atomicAdd(&red[1][colsv[k]], cs[k] * cs[k]);
    }
    __syncthreads();
    float* bank = stats + (blockIdx.x & (NBANK - 1)) * 192;
    if (tid < 96) {
        atomicAdd(&bank[tid], red[0][tid]);
        atomicAdd(&bank[96 + tid], red[1][tid]);
    }
}

// ---------------- fused BN+ReLU+residual + GEMM -> h1b (bf16), hwb (prescaled) -------
__global__ __launch_bounds__(256) void k_gemm_bn(const uint32_t* __restrict__ aggb,
                                                 const uint32_t* __restrict__ hprevb,
                                                 const float* __restrict__ stats,
                                                 const float* __restrict__ g,
                                                 const float* __restrict__ be,
                                                 const float* __restrict__ W,
                                                 const float* __restrict__ dinv,
                                                 uint32_t* __restrict__ hnewb,
                                                 uint32_t* __restrict__ hwb) {
    __shared__ float sAT[96][68];
    __shared__ float sW[96 * 96];
    __shared__ float ssc[96], ssh[96];
    int tid = threadIdx.x;
    int row0 = blockIdx.x * 64;

    for (int i = tid; i < 96 * 96; i += 256) sW[i] = W[i];
    if (tid < 96) {
        float s = 0.0f, s2 = 0.0f;
#pragma unroll
        for (int k = 0; k < NBANK; ++k) { s += stats[k * 192 + tid]; s2 += stats[k * 192 + 96 + tid]; }
        float m = s * (1.0f / NN);
        float var = s2 * (1.0f / NN) - m * m;
        float sc = g[tid] * rsqrtf(var + EPSV);
        ssc[tid] = sc;
        ssh[tid] = be[tid] - m * sc;
    }
    __syncthreads();

    // staging: unpack agg/hprev, BN+relu+residual -> hnewb + sAT
    for (int i = tid; i < 64 * 24; i += 256) {
        int r = i / 24, qq = i % 24;
        int gr = row0 + r, c = qq * 4, w0 = qq * 2;
        float v0 = 0.0f, v1 = 0.0f, v2 = 0.0f, v3 = 0.0f;
        if (gr < NN) {
            uint2 aw = *reinterpret_cast<const uint2*>(&aggb[(size_t)gr * HWS + w0]);
            uint2 pw = *reinterpret_cast<const uint2*>(&hprevb[(size_t)gr * HWS + w0]);
            v0 = fmaxf(blo(aw.x) * ssc[c]     + ssh[c],     0.0f) + blo(pw.x);
            v1 = fmaxf(bhi(aw.x) * ssc[c + 1] + ssh[c + 1], 0.0f) + bhi(pw.x);
            v2 = fmaxf(blo(aw.y) * ssc[c + 2] + ssh[c + 2], 0.0f) + blo(pw.y);
            v3 = fmaxf(bhi(aw.y) * ssc[c + 3] + ssh[c + 3], 0.0f) + bhi(pw.y);
            *reinterpret_cast<uint2*>(&hnewb[(size_t)gr * HWS + w0]) =
                make_uint2(packbf(v0, v1), packbf(v2, v3));
        }
        sAT[c][r] = v0; sAT[c + 1][r] = v1; sAT[c + 2][r] = v2; sAT[c + 3][r] = v3;
    }
    __syncthreads();

    int tc = tid & 15, tr = tid >> 4;
    int r0 = tr * 4, j0 = tc * 6;
    float acc[4][6];
#pragma unroll
    for (int i = 0; i < 4; ++i)
#pragma unroll
        for (int j = 0; j < 6; ++j) acc[i][j] = 0.0f;

    for (int k = 0; k < 96; ++k) {
        float4 a = *reinterpret_cast<const float4*>(&sAT[k][r0]);
        const float* wr = &sW[k * 96 + j0];
        float b0 = wr[0], b1 = wr[1], b2 = wr[2], b3 = wr[3], b4 = wr[4], b5 = wr[5];
        float av[4] = {a.x, a.y, a.z, a.w};
#pragma unroll
        for (int i = 0; i < 4; ++i) {
            acc[i][0] += av[i] * b0; acc[i][1] += av[i] * b1; acc[i][2] += av[i] * b2;
            acc[i][3] += av[i] * b3; acc[i][4] += av[i] * b4; acc[i][5] += av[i] * b5;
        }
    }
#pragma unroll
    for (int i = 0; i < 4; ++i) {
        int gr = row0 + r0 + i;
        if (gr < NN) {
            float dv = dinv[gr];
            uint32_t* wp = &hwb[(size_t)gr * HWS + tc * 3];
            wp[0] = packbf(acc[i][0] * dv, acc[i][1] * dv);
            wp[1] = packbf(acc[i][2] * dv, acc[i][3] * dv);
            wp[2] = packbf(acc[i][4] * dv, acc[i][5] * dv);
        }
    }
}

// ---------------- fused BN2 + pool + GEMM(96x192) + LayerNorm ----------------
__device__ inline int lower_bound_i(const int* __restrict__ a, int n, int v) {
    int lo = 0, hi = n;
    while (lo < hi) { int mid = (lo + hi) >> 1; if (a[mid] < v) lo = mid + 1; else hi = mid; }
    return lo;
}

__global__ __launch_bounds__(384) void k_out(const uint32_t* __restrict__ aggb,
                                             const uint32_t* __restrict__ hprevb,
                                             const float* __restrict__ stats,
                                             const float* __restrict__ g,
                                             const float* __restrict__ be,
                                             const int* __restrict__ batch,
                                             const float* __restrict__ Wout,
                                             const float* __restrict__ bout,
                                             const float* __restrict__ lg,
                                             const float* __restrict__ lb,
                                             float* __restrict__ out) {
    __shared__ float ssc[96], ssh[96];
    __shared__ float sp8[8][96];
    __shared__ float sp[96];
    __shared__ float svals[192];
    __shared__ float smv[2];
    int b = blockIdx.x, t = threadIdx.x;
    if (t < 96) {
        float s = 0.0f, s2 = 0.0f;
#pragma unroll
        for (int k = 0; k < NBANK; ++k) { s += stats[k * 192 + t]; s2 += stats[k * 192 + 96 + t]; }
        float m = s * (1.0f / NN);
        float var = s2 * (1.0f / NN) - m * m;
        float sc = g[t] * rsqrtf(var + EPSV);
        ssc[t] = sc;
        ssh[t] = be[t] - m * sc;
    }
    int lo = lower_bound_i(batch, NN, b);
    int hi = lower_bound_i(batch, NN, b + 1);
    __syncthreads();

    int w = t % 48, qr = t / 48;
    int c0 = 2 * w, c1 = 2 * w + 1;
    float sc0 = ssc[c0], sh0 = ssh[c0], sc1 = ssc[c1], sh1 = ssh[c1];
    float accp0 = 0.0f, accp1 = 0.0f;
    for (int r = lo + qr; r < hi; r += 8) {
        uint32_t a = aggb[(size_t)r * HWS + w];
        uint32_t h = hprevb[(size_t)r * HWS + w];
        accp0 += fmaxf(blo(a) * sc0 + sh0, 0.0f) + blo(h);
        accp1 += fmaxf(bhi(a) * sc1 + sh1, 0.0f) + bhi(h);
    }
    sp8[qr][c0] = accp0;
    sp8[qr][c1] = accp1;
    __syncthreads();
    if (t < 96) {
        float inv = (hi > lo) ? 1.0f / (float)(hi - lo) : 0.0f;
        float s = 0.0f;
#pragma unroll
        for (int k = 0; k < 8; ++k) s += sp8[k][t];
        sp[t] = s * inv;
    }
    __syncthreads();

    float acc = 0.0f;
    if (t < 192) {
        acc = bout[t];
        for (int k = 0; k < 96; ++k) acc += sp[k] * Wout[k * 192 + t];
        svals[t] = acc;
    }
    __syncthreads();
    if (t < 64) {
        float a0 = svals[t], a1 = svals[t + 64], a2 = svals[t + 128];
        float s = a0 + a1 + a2;
        float s2 = a0 * a0 + a1 * a1 + a2 * a2;
        for (int o = 32; o > 0; o >>= 1) {
            s += __shfl_down(s, o, 64);
            s2 += __shfl_down(s2, o, 64);
        }
        if (t == 0) { smv[0] = s * (1.0f / 192.0f); smv[1] = s2 * (1.0f / 192.0f); }
    }
    __syncthreads();
    if (t < 192) {
        float m = smv[0];
        float var = smv[1] - m * m;
        float rr = rsqrtf(var + EPSV);
        out[b * 192 + t] = lg[t] * (acc - m) * rr + lb[t];
    }
}

extern "C" void kernel_launch(void* const* d_in, const int* in_sizes, int n_in,
                              void* d_out, int out_size, void* d_ws, size_t ws_size,
                              hipStream_t stream) {
    const float* x    = (const float*)d_in[0];
    const int*   ei   = (const int*)  d_in[1];
    const int*   batch= (const int*)  d_in[2];
    const float* Win  = (const float*)d_in[3];
    const float* bin  = (const float*)d_in[4];
    const float* W1   = (const float*)d_in[5];
    const float* g1   = (const float*)d_in[7];
    const float* be1  = (const float*)d_in[8];
    const float* W2   = (const float*)d_in[9];
    const float* g2   = (const float*)d_in[11];
    const float* be2  = (const float*)d_in[12];
    const float* Wout = (const float*)d_in[13];
    const float* bout = (const float*)d_in[14];
    const float* lg   = (const float*)d_in[15];
    const float* lb   = (const float*)d_in[16];
    const int* src = ei;
    const int* dst = ei + EE;

    uint32_t* wsp    = (uint32_t*)d_ws;
    uint32_t* h0b    = wsp;                           // [N][48] bf16x2
    uint32_t* h1b    = h0b + (size_t)NN * HWS;        // [N][48]
    uint32_t* aggb   = h1b + (size_t)NN * HWS;        // [N][48] (reused both layers)
    uint32_t* hwb    = aggb + (size_t)NN * HWS;       // [N][48] prescaled
    float*    dinv   = (float*)(hwb + (size_t)NN * HWS);  // [N]
    float*    stats  = dinv + NN;                     // [2][NBANK][192]
    int*      degi   = (int*)(stats + 2 * NBANK * 192);   // [N]
    int*      histg  = degi + NN;                     // [NBLK_SCAN][64]
    int*      row_ptr= histg + NBLK_SCAN * 64;        // [N+1]
    int*      perm   = row_ptr + NN + 1;              // [N]
    int*      bkcnt  = perm + NN;                     // [NBUK]
    int*      bkbase = bkcnt + NBUK;                  // [NBUK+1]
    int*      bkcur  = bkbase + NBUK + 1;             // [NBUK]
    int*      col    = bkcur + NBUK;                  // [E]
    uint32_t* ebuf   = aggb;                          // [E] aliases aggb (dead until gather)

    const int TB = 256;
    float* stats1 = stats;
    float* stats2 = stats + NBANK * 192;

    // ---- CSR build (dst-grouped; shared by both layers) ----
    hipMemsetAsync(bkcnt, 0, NBUK * sizeof(int), stream);
    k_bhist<<<FILLB, TB, 0, stream>>>(dst, bkcnt);
    k_bscan<<<1, TB, 0, stream>>>(bkcnt, bkbase, bkcur, stats, row_ptr);
    k_bscat<<<FILLB, TB, 0, stream>>>(src, dst, bkcur, ebuf);
    k_csr<<<NBUK, TB, 0, stream>>>(ebuf, bkbase, row_ptr, col, degi, dinv);
    k_dhist<<<NBLK_SCAN, 1024, 0, stream>>>(degi, histg);
    k_dscan<<<1, 64, 0, stream>>>(histg);
    k_dperm<<<NBLK_SCAN, 1024, 0, stream>>>(degi, histg, perm);

    // ---- layer 0: input MLP + GEMM1 fused ----
    k_gemm_in<<<(NN + 63) / 64, TB, 0, stream>>>(x, Win, bin, W1, dinv, h0b, hwb);
    k_gather<<<NB_GATHER, TB, 0, stream>>>(hwb, dinv, row_ptr, col, perm, aggb, stats1);

    // ---- layer 1: BN1+res fused into GEMM2 ----
    k_gemm_bn<<<(NN + 63) / 64, TB, 0, stream>>>(aggb, h0b, stats1, g1, be1, W2, dinv,
                                                 h1b, hwb);
    k_gather<<<NB_GATHER, TB, 0, stream>>>(hwb, dinv, row_ptr, col, perm, aggb, stats2);

    // ---- BN2+res fused into pool + readout + layernorm ----
    k_out<<<BB, 384, 0, stream>>>(aggb, h1b, stats2, g2, be2, batch, Wout, bout, lg, lb,
                                  (float*)d_out);
}